// Round 13
// baseline (456.564 us; speedup 1.0000x reference)
//
#include <hip/hip_runtime.h>
#include <math.h>

#define NPB   1024          // nodes per batch/event
#define NB    32            // batches
#define NTOT  (NPB * NB)    // 32768 nodes
#define KNN_K 30
#define QB    8             // queries per fused-kNN block (33 KB LDS -> 4 blocks/CU)
#define DSTR  1028          // LDS d2 row stride (words) -> conflict-free
#define FINF  __builtin_inff()

typedef __attribute__((ext_vector_type(8))) short bf16x8;
typedef __attribute__((ext_vector_type(4))) float f32x4;
typedef unsigned short ushort_t;

__device__ inline ushort_t f2bf(float f) {          // RNE f32 -> bf16
  unsigned u = __builtin_bit_cast(unsigned, f);
  u += 0x7FFFu + ((u >> 16) & 1u);
  return (ushort_t)(u >> 16);
}
__device__ inline float bf2f(ushort_t h) {
  return __builtin_bit_cast(float, (unsigned)h << 16);
}
__device__ inline unsigned packkey(float d, int col) { // order-preserving + idx
  unsigned u = __builtin_bit_cast(unsigned, d);
  u ^= ((unsigned)((int)u >> 31) | 0x80000000u);
  return (u & 0xFFFFFC00u) | (unsigned)col;
}

// ---------------------------------------------------------------------------
// select_row_packed: exact top-30 of 1024 packed keys (LDS row), 1 wave.
// Keys unique (col in low 10 bits). Per-lane min -> bitonic-64 -> T (>= true
// rank-30 key) -> compact survivors via shfl-scan into the row's OWN LDS
// (row data already in registers) -> bitonic-64 sort (survivors ~40; 128-wide
// and extraction fallbacks kept for the astronomically rare overflow cases).
// ---------------------------------------------------------------------------
__device__ __forceinline__ void select_row_packed(unsigned* row, int jbase,
                                                  int* out, int lane) {
  unsigned u[16];
  #pragma unroll
  for (int i = 0; i < 16; ++i) u[i] = row[lane + (i << 6)];

  unsigned m = u[0];
  #pragma unroll
  for (int i = 1; i < 16; ++i) m = min(m, u[i]);
  #pragma unroll
  for (int k = 2; k <= 64; k <<= 1) {
    #pragma unroll
    for (int jj = k >> 1; jj >= 1; jj >>= 1) {
      const unsigned o = (unsigned)__shfl_xor((int)m, jj);
      const bool up    = ((lane & k) == 0);
      const bool lower = ((lane & jj) == 0);
      m = (lower == up) ? min(m, o) : max(m, o);
    }
  }
  const unsigned T = (unsigned)__shfl((int)m, 29);   // >= true rank-30 key

  unsigned mask16 = 0; int cnt = 0;
  #pragma unroll
  for (int i = 0; i < 16; ++i) {
    const bool sv = (u[i] <= T);
    mask16 |= (sv ? 1u : 0u) << i;
    cnt += sv;
  }
  int sc = cnt;
  #pragma unroll
  for (int o = 1; o < 64; o <<= 1) {
    const int v = __shfl_up(sc, o);
    if (lane >= o) sc += v;
  }
  const int base = sc - cnt;
  const int tot  = __shfl(sc, 63);
  unsigned* cb = row;                         // row data lives in regs now

  if (tot <= 64) {                            // ~always (survivors ~40±6)
    int p = base;
    #pragma unroll
    for (int i = 0; i < 16; ++i) {
      if ((mask16 >> i) & 1u) cb[p++] = u[i];
    }
    if (tot + lane < 64) cb[tot + lane] = 0xFFFFFFFFu;
    unsigned r0 = cb[lane];
    #pragma unroll
    for (int k = 2; k <= 64; k <<= 1) {
      #pragma unroll
      for (int jj = k >> 1; jj >= 1; jj >>= 1) {
        const unsigned o = (unsigned)__shfl_xor((int)r0, jj);
        const bool up    = ((lane & k) == 0);
        const bool lower = ((lane & jj) == 0);
        r0 = (lower == up) ? min(r0, o) : max(r0, o);
      }
    }
    if (lane < KNN_K) out[lane] = jbase + (int)(r0 & 1023u);
  } else if (tot <= 128) {
    int p = base;
    #pragma unroll
    for (int i = 0; i < 16; ++i) {
      if ((mask16 >> i) & 1u) cb[p++] = u[i];
    }
    for (int q = tot + lane; q < 128; q += 64) cb[q] = 0xFFFFFFFFu;
    unsigned r0 = cb[lane];
    unsigned r1 = cb[lane + 64];
    #pragma unroll
    for (int k = 2; k <= 128; k <<= 1) {
      #pragma unroll
      for (int jj = k >> 1; jj >= 1; jj >>= 1) {
        if (jj == 64) {
          const unsigned lo = min(r0, r1), hi = max(r0, r1);
          r0 = lo; r1 = hi;
        } else {
          const unsigned o0 = (unsigned)__shfl_xor((int)r0, jj);
          const unsigned o1 = (unsigned)__shfl_xor((int)r1, jj);
          const bool lower = ((lane & jj) == 0);
          const bool up0 = ((lane & k) == 0);
          const bool up1 = (((lane + 64) & k) == 0);
          r0 = (lower == up0) ? min(r0, o0) : max(r0, o0);
          r1 = (lower == up1) ? min(r1, o1) : max(r1, o1);
        }
      }
    }
    if (lane < KNN_K) out[lane] = jbase + (int)(r0 & 1023u);
  } else {                                    // exact fallback (never in practice)
    unsigned pk[16];
    #pragma unroll
    for (int i = 0; i < 16; ++i) pk[i] = u[i];
    #pragma unroll 1
    for (int k = 0; k < KNN_K; ++k) {
      unsigned best = pk[0];
      #pragma unroll
      for (int i = 1; i < 16; ++i) best = min(best, pk[i]);
      #pragma unroll
      for (int o = 32; o > 0; o >>= 1)
        best = min(best, (unsigned)__shfl_xor((int)best, o));
      if (lane == 0) out[k] = jbase + (int)(best & 1023u);
      #pragma unroll
      for (int i = 0; i < 16; ++i) if (pk[i] == best) pk[i] = 0xFFFFFFFFu;
    }
  }
}

// ---------------------------------------------------------------------------
// knn64: fused distance+select for bf16 D=64 features. One block = 8 queries.
// Phase 1: each wave computes an 8x128 chunk of D2 via 16x16x32 MFMA (top
// half of the 16-row tile; bottom rows masked) and writes PACKED keys to LDS.
// Phase 2: each wave selects top-30 for 1 row. 33 KB LDS -> 4 blocks/CU.
// Grid (NPB/QB, NB), 512 threads.
// ---------------------------------------------------------------------------
__global__ __launch_bounds__(512)
void knn64_kernel(const ushort_t* __restrict__ X, int lda,
                  const float* __restrict__ sq, int* __restrict__ idx) {
  __shared__ unsigned d2l[QB * DSTR];
  __shared__ float sqa[QB];
  const int tid = threadIdx.x;
  const int wave = tid >> 6, lane = tid & 63;
  const int g = lane >> 4, r16 = lane & 15;
  const int nbase = blockIdx.y * NPB;
  const int q0 = blockIdx.x * QB;
  if (tid < QB) sqa[tid] = sq[nbase + q0 + tid];
  __syncthreads();

  const int n0 = wave * 128;
  const int qr = (r16 < QB) ? r16 : QB - 1;   // clamp: rows >= QB are unused
  bf16x8 a0[2];
  #pragma unroll
  for (int ks = 0; ks < 2; ++ks)
    a0[ks] = *(const bf16x8*)(X + (size_t)(nbase + q0 + qr) * lda + ks * 32 + g * 8);

  #pragma unroll
  for (int nt = 0; nt < 8; ++nt) {
    const int col = n0 + nt * 16 + r16;
    f32x4 acc0 = (f32x4)(0.f);
    #pragma unroll
    for (int ks = 0; ks < 2; ++ks) {
      const bf16x8 b = *(const bf16x8*)(X + (size_t)(nbase + col) * lda + ks * 32 + g * 8);
      acc0 = __builtin_amdgcn_mfma_f32_16x16x32_bf16(a0[ks], b, acc0, 0, 0, 0);
    }
    const float sb = sq[nbase + col];
    #pragma unroll
    for (int r = 0; r < 4; ++r) {
      const int row0 = g * 4 + r;
      if (row0 < QB)
        d2l[row0 * DSTR + col] = packkey(sqa[row0] + sb - 2.f * acc0[r], col);
    }
  }
  __syncthreads();

  const int row = wave;                       // 8 waves, 8 rows
  select_row_packed(&d2l[row * DSTR], nbase,
                    idx + (size_t)(nbase + q0 + row) * KNN_K, lane);
}

// ---------------------------------------------------------------------------
// knn7: fused distance+select for fp32 D=7 (conv1, exact distances). One
// block = 8 queries; wave computes 2 cols x 8 rows (fp32 FMA, d-ascending
// order preserved), packs keys to LDS, then selects 1 row. 512 threads.
// ---------------------------------------------------------------------------
__global__ __launch_bounds__(512)
void knn7_kernel(const float* __restrict__ pos,
                 const float* __restrict__ sq, int* __restrict__ idx) {
  __shared__ unsigned d2l[QB * DSTR];
  __shared__ float Xq[QB][8];
  __shared__ float sqa[QB];
  const int tid = threadIdx.x;
  const int wave = tid >> 6, lane = tid & 63;
  const int nbase = blockIdx.y * NPB;
  const int q0 = blockIdx.x * QB;
  if (tid < QB * 8) {
    const int row = tid >> 3, d = tid & 7;
    Xq[row][d] = (d < 7) ? pos[(size_t)(nbase + q0 + row) * 7 + d] : 0.f;
  }
  if (tid >= 64 && tid < 64 + QB) sqa[tid - 64] = sq[nbase + q0 + tid - 64];
  __syncthreads();

  const int c0 = wave * 128 + lane;           // two cols: c0, c0+64
  float xc0[7], xc1[7];
  #pragma unroll
  for (int d = 0; d < 7; ++d) {
    xc0[d] = pos[(size_t)(nbase + c0) * 7 + d];
    xc1[d] = pos[(size_t)(nbase + c0 + 64) * 7 + d];
  }
  const float sb0 = sq[nbase + c0], sb1 = sq[nbase + c0 + 64];
  #pragma unroll
  for (int row = 0; row < QB; ++row) {
    float q[7];
    #pragma unroll
    for (int d = 0; d < 7; ++d) q[d] = Xq[row][d];
    float d0 = 0.f, d1 = 0.f;
    #pragma unroll
    for (int d = 0; d < 7; ++d) { d0 += q[d] * xc0[d]; d1 += q[d] * xc1[d]; }
    const float sa = sqa[row];
    d2l[row * DSTR + c0]      = packkey(sa + sb0 - 2.f * d0, c0);
    d2l[row * DSTR + c0 + 64] = packkey(sa + sb1 - 2.f * d1, c0 + 64);
  }
  __syncthreads();

  const int row = wave;
  select_row_packed(&d2l[row * DSTR], nbase,
                    idx + (size_t)(nbase + q0 + row) * KNN_K, lane);
}

// ---------------------------------------------------------------------------
// sq (f32 / bf16 input): ||x||^2 per node (kNN path).
// ---------------------------------------------------------------------------
template<int D>
__global__ __launch_bounds__(256)
void sq_kernel(const float* __restrict__ x, int lda, float* __restrict__ sq) {
  const int wave = threadIdx.x >> 6, c = threadIdx.x & 63;
  const int nb = blockIdx.x * 16 + wave * 4;
  #pragma unroll
  for (int i = 0; i < 4; ++i) {
    const float xv = (c < D) ? x[(size_t)(nb + i) * lda + c] : 0.f;
    float p = xv * xv;
    #pragma unroll
    for (int o = 32; o > 0; o >>= 1) p += __shfl_down(p, o);
    if (c == 0) sq[nb + i] = p;
  }
}
__global__ __launch_bounds__(256)
void sqbf_kernel(const ushort_t* __restrict__ x, int lda, float* __restrict__ sq) {
  const int wave = threadIdx.x >> 6, c = threadIdx.x & 63;
  const int nb = blockIdx.x * 16 + wave * 4;
  #pragma unroll
  for (int i = 0; i < 4; ++i) {
    const float xv = bf2f(x[(size_t)(nb + i) * lda + c]);
    float p = xv * xv;
    #pragma unroll
    for (int o = 32; o > 0; o >>= 1) p += __shfl_down(p, o);
    if (c == 0) sq[nb + i] = p;
  }
}

// ---------------------------------------------------------------------------
// wprep / pospad / wcvt: weight & input prep (BN folded, bf16, transposed).
// ---------------------------------------------------------------------------
__global__ __launch_bounds__(256)
void wprep_kernel(const float* __restrict__ W1, const float* __restrict__ b1,
                  const float* __restrict__ s, const float* __restrict__ t,
                  int D, ushort_t* __restrict__ BTc, float* __restrict__ biasc) {
  const int i = blockIdx.x * 256 + threadIdx.x;
  if (i >= 128 * 64) return;
  const int n = i >> 6, k = i & 63;
  float v = 0.f;
  if (k < D) {
    if (n < 64) v = (W1[k * 64 + n] - W1[(D + k) * 64 + n]) * s[n];
    else        v = W1[(D + k) * 64 + (n - 64)] * s[n - 64];
  }
  BTc[i] = f2bf(v);
  if (k == 0) biasc[n] = (n < 64) ? (b1[n] * s[n] + t[n]) : 0.f;
}

__global__ __launch_bounds__(256)
void pospad_kernel(const float* __restrict__ pos, ushort_t* __restrict__ xpad) {
  const int i = blockIdx.x * 256 + threadIdx.x;
  const int node = i >> 6, k = i & 63;
  xpad[i] = f2bf(k < 7 ? pos[(size_t)node * 7 + k] : 0.f);
}

__global__ __launch_bounds__(256)
void wcvt_kernel(const float* __restrict__ W, ushort_t* __restrict__ BT,
                 int K, int N) {
  const int i = blockIdx.x * 256 + threadIdx.x;
  if (i >= N * K) return;
  const int n = i / K, k = i % K;
  BT[i] = f2bf(W[(size_t)k * N + n]);
}

// ---------------------------------------------------------------------------
// edge (MFMA): per node, H[32 edges][64] @ W2[64][64] -> col-max over edges.
// W2T pre-transposed bf16 [n][k]; 4 nodes per wave. av[node][128]: as|vs.
// ---------------------------------------------------------------------------
__global__ __launch_bounds__(256)
void edge_mfma_kernel(const ushort_t* __restrict__ av,
                      const int* __restrict__ idx,
                      const ushort_t* __restrict__ W2T, const float* __restrict__ b2,
                      ushort_t* __restrict__ xbf) {
  const int lane = threadIdx.x & 63;
  const int wave = threadIdx.x >> 6;
  const int g = lane >> 4, r16 = lane & 15;
  const int node0 = blockIdx.x * 16 + wave * 4;

  bf16x8 bf[2][4];
  #pragma unroll
  for (int ks = 0; ks < 2; ++ks)
    #pragma unroll
    for (int nt = 0; nt < 4; ++nt)
      bf[ks][nt] = *(const bf16x8*)(W2T + (nt * 16 + r16) * 64 + ks * 32 + g * 8);

  const float b2c = b2[lane];

  #pragma unroll 1
  for (int nn = 0; nn < 4; ++nn) {
    const int node = node0 + nn;
    float asf[2][8];
    {
      const ushort_t* ar = av + (size_t)node * 128;
      #pragma unroll
      for (int ks = 0; ks < 2; ++ks) {
        union { uint4 v; ushort_t s[8]; } u;
        u.v = *(const uint4*)(ar + ks * 32 + g * 8);
        #pragma unroll
        for (int i = 0; i < 8; ++i) asf[ks][i] = bf2f(u.s[i]);
      }
    }
    const int j0 = idx[(size_t)node * KNN_K + r16];
    const int e1 = 16 + r16;
    const int j1 = idx[(size_t)node * KNN_K + (e1 < KNN_K ? e1 : KNN_K - 1)];

    f32x4 acc[2][4];
    #pragma unroll
    for (int mt = 0; mt < 2; ++mt)
      #pragma unroll
      for (int nt = 0; nt < 4; ++nt) acc[mt][nt] = (f32x4)(0.f);

    #pragma unroll
    for (int mt = 0; mt < 2; ++mt) {
      const int j = mt ? j1 : j0;
      const ushort_t* vr = av + (size_t)j * 128 + 64;
      #pragma unroll
      for (int ks = 0; ks < 2; ++ks) {
        union { uint4 v; ushort_t s[8]; } u;
        u.v = *(const uint4*)(vr + ks * 32 + g * 8);
        bf16x8 af;
        #pragma unroll
        for (int i = 0; i < 8; ++i) {
          const float hh = fmaxf(asf[ks][i] + bf2f(u.s[i]), 0.f);
          af[i] = (short)f2bf(hh);
        }
        #pragma unroll
        for (int nt = 0; nt < 4; ++nt)
          acc[mt][nt] = __builtin_amdgcn_mfma_f32_16x16x32_bf16(af, bf[ks][nt], acc[mt][nt], 0, 0, 0);
      }
    }

    float cm[4];
    #pragma unroll
    for (int nt = 0; nt < 4; ++nt) {
      float m0 = fmaxf(fmaxf(acc[0][nt][0], acc[0][nt][1]), fmaxf(acc[0][nt][2], acc[0][nt][3]));
      float m1 = fmaxf(fmaxf(acc[1][nt][0], acc[1][nt][1]), fmaxf(acc[1][nt][2], acc[1][nt][3]));
      float m = fmaxf(m0, m1);
      m = fmaxf(m, __shfl_xor(m, 16));
      m = fmaxf(m, __shfl_xor(m, 32));
      cm[nt] = m;
    }
    const float v = (g == 0) ? cm[0] : (g == 1) ? cm[1] : (g == 2) ? cm[2] : cm[3];
    xbf[(size_t)node * 192 + lane] = f2bf(v + b2c);
  }
}

// ---------------------------------------------------------------------------
// bf16 MFMA GEMM: C = relu?(A[M,K]bf16 @ B + bias). B passed as BT[N][K] bf16.
// BM=128 BN=128 BK=64, 4 waves (2x2), wave tile 64x64.
// ---------------------------------------------------------------------------
template<bool RELU, typename CT>
__global__ __launch_bounds__(256)
void gemm_bf16_kernel(const ushort_t* __restrict__ A, int lda,
                      const ushort_t* __restrict__ BT, int ldb,
                      const float* __restrict__ bias,
                      CT* __restrict__ C, int ldc, int K) {
  __shared__ ushort_t As[128 * 72];
  __shared__ ushort_t Bs[128 * 72];
  const int tid = threadIdx.x;
  const int lane = tid & 63;
  const int g = lane >> 4, r16 = lane & 15;
  const int wv = tid >> 6, wm = wv >> 1, wn = wv & 1;
  const int bm = blockIdx.x * 128, bn = blockIdx.y * 128;

  f32x4 acc[4][4];
  #pragma unroll
  for (int mt = 0; mt < 4; ++mt)
    #pragma unroll
    for (int nt = 0; nt < 4; ++nt) acc[mt][nt] = (f32x4)(0.f);

  const int srow = tid >> 1, scq = (tid & 1) * 32;
  for (int k0 = 0; k0 < K; k0 += 64) {
    const ushort_t* ap = A + (size_t)(bm + srow) * lda + k0 + scq;
    const ushort_t* bp = BT + (size_t)(bn + srow) * ldb + k0 + scq;
    uint4 av0 = *(const uint4*)(ap);      uint4 av1 = *(const uint4*)(ap + 8);
    uint4 av2 = *(const uint4*)(ap + 16); uint4 av3 = *(const uint4*)(ap + 24);
    uint4 bv0 = *(const uint4*)(bp);      uint4 bv1 = *(const uint4*)(bp + 8);
    uint4 bv2 = *(const uint4*)(bp + 16); uint4 bv3 = *(const uint4*)(bp + 24);
    __syncthreads();
    *(uint4*)(As + srow * 72 + scq +  0) = av0;
    *(uint4*)(As + srow * 72 + scq +  8) = av1;
    *(uint4*)(As + srow * 72 + scq + 16) = av2;
    *(uint4*)(As + srow * 72 + scq + 24) = av3;
    *(uint4*)(Bs + srow * 72 + scq +  0) = bv0;
    *(uint4*)(Bs + srow * 72 + scq +  8) = bv1;
    *(uint4*)(Bs + srow * 72 + scq + 16) = bv2;
    *(uint4*)(Bs + srow * 72 + scq + 24) = bv3;
    __syncthreads();
    #pragma unroll
    for (int ks = 0; ks < 2; ++ks) {
      bf16x8 a[4], b[4];
      #pragma unroll
      for (int mt = 0; mt < 4; ++mt)
        a[mt] = *(const bf16x8*)(As + (wm * 64 + mt * 16 + r16) * 72 + ks * 32 + g * 8);
      #pragma unroll
      for (int nt = 0; nt < 4; ++nt)
        b[nt] = *(const bf16x8*)(Bs + (wn * 64 + nt * 16 + r16) * 72 + ks * 32 + g * 8);
      #pragma unroll
      for (int mt = 0; mt < 4; ++mt)
        #pragma unroll
        for (int nt = 0; nt < 4; ++nt)
          acc[mt][nt] = __builtin_amdgcn_mfma_f32_16x16x32_bf16(a[mt], b[nt], acc[mt][nt], 0, 0, 0);
    }
  }

  #pragma unroll
  for (int nt = 0; nt < 4; ++nt) {
    const int col = bn + wn * 64 + nt * 16 + r16;
    const float bv = bias[col];
    #pragma unroll
    for (int mt = 0; mt < 4; ++mt) {
      #pragma unroll
      for (int r = 0; r < 4; ++r) {
        const int row = bm + wm * 64 + mt * 16 + g * 4 + r;
        float val = acc[mt][nt][r] + bv;
        if (RELU) val = fmaxf(val, 0.f);
        if constexpr (sizeof(CT) == 2) C[(size_t)row * ldc + col] = f2bf(val);
        else                           C[(size_t)row * ldc + col] = val;
      }
    }
  }
}

// ---------------------------------------------------------------------------
// g4: logits = h3[row](bf16) @ W4[128,2] + b4 ; log_softmax. 4 rows/block.
// ---------------------------------------------------------------------------
__global__ __launch_bounds__(256)
void g4_kernel(const ushort_t* __restrict__ h3, const float* __restrict__ W4,
               const float* __restrict__ b4, float* __restrict__ seg) {
  const int row = blockIdx.x * 4 + (threadIdx.x >> 6);
  const int lane = threadIdx.x & 63;
  const ushort_t* hr = h3 + (size_t)row * 128;
  float p0 = 0.f, p1 = 0.f;
  #pragma unroll
  for (int h = 0; h < 2; ++h) {
    const int r = lane + h * 64;
    const float hv = bf2f(hr[r]);
    p0 += hv * W4[r * 2 + 0];
    p1 += hv * W4[r * 2 + 1];
  }
  #pragma unroll
  for (int o = 32; o > 0; o >>= 1) { p0 += __shfl_down(p0, o); p1 += __shfl_down(p1, o); }
  if (lane == 0) {
    const float l0 = p0 + b4[0], l1 = p1 + b4[1];
    const float mx = fmaxf(l0, l1);
    const float lse = mx + logf(expf(l0 - mx) + expf(l1 - mx));
    seg[(size_t)row * 2 + 0] = l0 - lse;
    seg[(size_t)row * 2 + 1] = l1 - lse;
  }
}

// ---------------------------------------------------------------------------
// wrapper: per event: y = relu(flat @ mW1 + mb1) @ mW2 + mb2 ; log_softmax.
// ---------------------------------------------------------------------------
__global__ __launch_bounds__(256)
void wrapper_kernel(const float* __restrict__ seg, const float* __restrict__ W1,
                    const float* __restrict__ b1, const float* __restrict__ W2,
                    const float* __restrict__ b2, float* __restrict__ out) {
  __shared__ float fl[NPB * 2];
  __shared__ float part[2][128];
  __shared__ float y1[100];
  __shared__ float l2[2];
  const int b = blockIdx.x, tid = threadIdx.x;
  for (int i = tid; i < NPB * 2; i += 256) fl[i] = seg[(size_t)b * NPB * 2 + i];
  __syncthreads();
  {
    const int c = tid & 127, p = tid >> 7;
    float acc = 0.f;
    if (c < 100) {
      const int r0 = p * (NPB);
      #pragma unroll 16
      for (int r = 0; r < NPB; ++r)
        acc += fl[r0 + r] * W1[(size_t)(r0 + r) * 100 + c];
    }
    part[p][c] = acc;
  }
  __syncthreads();
  if (tid < 100) {
    y1[tid] = fmaxf(part[0][tid] + part[1][tid] + b1[tid], 0.f);
  }
  __syncthreads();
  if (tid < 2) {
    float acc = b2[tid];
    for (int j = 0; j < 100; ++j) acc += y1[j] * W2[j * 2 + tid];
    l2[tid] = acc;
  }
  __syncthreads();
  if (tid == 0) {
    const float l0 = l2[0], l1 = l2[1];
    const float mx = fmaxf(l0, l1);
    const float lse = mx + logf(expf(l0 - mx) + expf(l1 - mx));
    out[b * 2 + 0] = l0 - lse;
    out[b * 2 + 1] = l1 - lse;
  }
}

// ---------------------------------------------------------------------------
extern "C" void kernel_launch(void* const* d_in, const int* in_sizes, int n_in,
                              void* d_out, int out_size, void* d_ws, size_t ws_size,
                              hipStream_t stream) {
  const float* pos   = (const float*)d_in[0];
  const float* c1_W1 = (const float*)d_in[3];
  const float* c1_b1 = (const float*)d_in[4];
  const float* c1_s  = (const float*)d_in[5];
  const float* c1_t  = (const float*)d_in[6];
  const float* c1_W2 = (const float*)d_in[7];
  const float* c1_b2 = (const float*)d_in[8];
  const float* c2_W1 = (const float*)d_in[9];
  const float* c2_b1 = (const float*)d_in[10];
  const float* c2_s  = (const float*)d_in[11];
  const float* c2_t  = (const float*)d_in[12];
  const float* c2_W2 = (const float*)d_in[13];
  const float* c2_b2 = (const float*)d_in[14];
  const float* c3_W1 = (const float*)d_in[15];
  const float* c3_b1 = (const float*)d_in[16];
  const float* c3_s  = (const float*)d_in[17];
  const float* c3_t  = (const float*)d_in[18];
  const float* c3_W2 = (const float*)d_in[19];
  const float* c3_b2 = (const float*)d_in[20];
  const float* h_W1  = (const float*)d_in[21];
  const float* h_b1  = (const float*)d_in[22];
  const float* h_W2  = (const float*)d_in[23];
  const float* h_b2  = (const float*)d_in[24];
  const float* h_W3  = (const float*)d_in[25];
  const float* h_b3  = (const float*)d_in[26];
  const float* h_W4  = (const float*)d_in[27];
  const float* h_b4  = (const float*)d_in[28];
  const float* m_W1  = (const float*)d_in[29];
  const float* m_b1  = (const float*)d_in[30];
  const float* m_W2  = (const float*)d_in[31];
  const float* m_b2  = (const float*)d_in[32];

  float* ws = (float*)d_ws;
  size_t off = 0;
  auto alloc = [&](size_t n) {
    float* p = ws + off;
    off += (n + 63) & ~(size_t)63;
    return p;
  };
  ushort_t* xbf   = (ushort_t*)alloc((size_t)NTOT * 96);  // bf16 features [NTOT][192]
  int*      idx   = (int*)alloc((size_t)NTOT * KNN_K);
  ushort_t* avbuf = (ushort_t*)alloc((size_t)NTOT * 64);  // as|vs bf16 [NTOT][128]
  ushort_t* xpad  = (ushort_t*)alloc((size_t)NTOT * 32);  // pos bf16 [NTOT][64]
  float*    sqb   = alloc(NTOT);
  float*    seg   = alloc((size_t)NTOT * 2);
  ushort_t* BT1   = (ushort_t*)alloc(1024 * 192 / 2);
  ushort_t* BT2   = (ushort_t*)alloc(256 * 1024 / 2);
  ushort_t* BT3   = (ushort_t*)alloc(128 * 256 / 2);
  ushort_t* BTc1  = (ushort_t*)alloc(128 * 64 / 2);
  ushort_t* BTc2  = (ushort_t*)alloc(128 * 64 / 2);
  ushort_t* BTc3  = (ushort_t*)alloc(128 * 64 / 2);
  ushort_t* W2T1  = (ushort_t*)alloc(64 * 64 / 2);
  ushort_t* W2T2  = (ushort_t*)alloc(64 * 64 / 2);
  ushort_t* W2T3  = (ushort_t*)alloc(64 * 64 / 2);
  float*    bc1   = alloc(128);
  float*    bc2   = alloc(128);
  float*    bc3   = alloc(128);

  // Head activations.
  const size_t totf = ws_size / 4;
  const size_t avail = (totf > off + 1024) ? (totf - off - 1024) : 0;
  int CH = 1;
  while (CH < 256 && (size_t)(NTOT / CH) * 704 > avail) CH <<= 1;
  const int CR = NTOT / CH;
  ushort_t* h1 = (ushort_t*)(ws + off);
  ushort_t* h2 = h1 + (size_t)CR * 1024;
  ushort_t* h3 = h2 + (size_t)CR * 256;

  // ---- one-time prep (deterministic every launch)
  wcvt_kernel<<<(192 * 1024 + 255) / 256, 256, 0, stream>>>(h_W1, BT1, 192, 1024);
  wcvt_kernel<<<(1024 * 256 + 255) / 256, 256, 0, stream>>>(h_W2, BT2, 1024, 256);
  wcvt_kernel<<<(256 * 128 + 255) / 256, 256, 0, stream>>>(h_W3, BT3, 256, 128);
  wcvt_kernel<<<16, 256, 0, stream>>>(c1_W2, W2T1, 64, 64);
  wcvt_kernel<<<16, 256, 0, stream>>>(c2_W2, W2T2, 64, 64);
  wcvt_kernel<<<16, 256, 0, stream>>>(c3_W2, W2T3, 64, 64);
  wprep_kernel<<<32, 256, 0, stream>>>(c1_W1, c1_b1, c1_s, c1_t, 7,  BTc1, bc1);
  wprep_kernel<<<32, 256, 0, stream>>>(c2_W1, c2_b1, c2_s, c2_t, 64, BTc2, bc2);
  wprep_kernel<<<32, 256, 0, stream>>>(c3_W1, c3_b1, c3_s, c3_t, 64, BTc3, bc3);
  pospad_kernel<<<NTOT * 64 / 256, 256, 0, stream>>>(pos, xpad);

  // as/vs GEMM: avbuf[NTOT][128] = A[NTOT][64] @ BTc^T + bias
  auto run_av = [&](const ushort_t* A, int lda, const ushort_t* BTc, const float* bc) {
    gemm_bf16_kernel<false, ushort_t><<<dim3(NTOT / 128, 1), 256, 0, stream>>>(
        A, lda, BTc, 64, bc, avbuf, 128, 64);
  };

  // ---- conv1 (pos f32 exact kNN, D=7) -> xbf cols 0..63
  sq_kernel<7><<<NTOT / 16, 256, 0, stream>>>(pos, 7, sqb);
  run_av(xpad, 64, BTc1, bc1);
  knn7_kernel<<<dim3(NPB / QB, NB), 512, 0, stream>>>(pos, sqb, idx);
  edge_mfma_kernel<<<NTOT / 16, 256, 0, stream>>>(avbuf, idx, W2T1, c1_b2, xbf + 0);

  // ---- conv2 (x1 bf16, D=64) -> cols 64..127
  sqbf_kernel<<<NTOT / 16, 256, 0, stream>>>(xbf + 0, 192, sqb);
  run_av(xbf + 0, 192, BTc2, bc2);
  knn64_kernel<<<dim3(NPB / QB, NB), 512, 0, stream>>>(xbf + 0, 192, sqb, idx);
  edge_mfma_kernel<<<NTOT / 16, 256, 0, stream>>>(avbuf, idx, W2T2, c2_b2, xbf + 64);

  // ---- conv3 (x2 bf16, D=64) -> cols 128..191
  sqbf_kernel<<<NTOT / 16, 256, 0, stream>>>(xbf + 64, 192, sqb);
  run_av(xbf + 64, 192, BTc3, bc3);
  knn64_kernel<<<dim3(NPB / QB, NB), 512, 0, stream>>>(xbf + 64, 192, sqb, idx);
  edge_mfma_kernel<<<NTOT / 16, 256, 0, stream>>>(avbuf, idx, W2T3, c3_b2, xbf + 128);

  // ---- head MLP (bf16 MFMA, chunked) + per-node log_softmax
  for (int ch = 0; ch < CH; ++ch) {
    const ushort_t* Ax = xbf + (size_t)ch * CR * 192;
    gemm_bf16_kernel<true, ushort_t><<<dim3(CR / 128, 8), 256, 0, stream>>>(Ax, 192, BT1, 192, h_b1, h1, 1024, 192);
    gemm_bf16_kernel<true, ushort_t><<<dim3(CR / 128, 2), 256, 0, stream>>>(h1, 1024, BT2, 1024, h_b2, h2, 256, 1024);
    gemm_bf16_kernel<true, ushort_t><<<dim3(CR / 128, 1), 256, 0, stream>>>(h2, 256, BT3, 256, h_b3, h3, 128, 256);
    g4_kernel<<<CR / 4, 256, 0, stream>>>(h3, h_W4, h_b4, seg + (size_t)ch * CR * 2);
  }

  // ---- wrapper MLP per event
  wrapper_kernel<<<NB, 256, 0, stream>>>(seg, m_W1, m_b1, m_W2, m_b2, (float*)d_out);
}

// Round 14
// 393.519 us; speedup vs baseline: 1.1602x; 1.1602x over previous
//
#include <hip/hip_runtime.h>
#include <math.h>

#define NPB   1024          // nodes per batch/event
#define NB    32            // batches
#define NTOT  (NPB * NB)    // 32768 nodes
#define KNN_K 30
#define QB    16            // queries per fused-kNN block (66 KB LDS -> 2 blocks/CU)
#define DSTR  1028          // LDS d2 row stride (words) -> conflict-free
#define FINF  __builtin_inff()

typedef __attribute__((ext_vector_type(8))) short bf16x8;
typedef __attribute__((ext_vector_type(4))) float f32x4;
typedef unsigned short ushort_t;

__device__ inline ushort_t f2bf(float f) {          // RNE f32 -> bf16
  unsigned u = __builtin_bit_cast(unsigned, f);
  u += 0x7FFFu + ((u >> 16) & 1u);
  return (ushort_t)(u >> 16);
}
__device__ inline float bf2f(ushort_t h) {
  return __builtin_bit_cast(float, (unsigned)h << 16);
}
__device__ inline unsigned packkey(float d, int col) { // order-preserving + idx
  unsigned u = __builtin_bit_cast(unsigned, d);
  u ^= ((unsigned)((int)u >> 31) | 0x80000000u);
  return (u & 0xFFFFFC00u) | (unsigned)col;
}

// ---------------------------------------------------------------------------
// select_row_packed: exact top-30 of 1024 packed keys (LDS row), 1 wave.
// Keys unique (col in low 10 bits). Per-lane min -> bitonic-64 -> T (>= true
// rank-30 key) -> compact survivors via shfl-scan into the row's OWN LDS
// (row already in registers) -> bitonic-64 sort (survivors ~40±6); 128-wide
// and extraction fallbacks for the astronomically rare overflow cases.
// ---------------------------------------------------------------------------
__device__ __forceinline__ void select_row_packed(unsigned* row, int jbase,
                                                  int* out, int lane) {
  unsigned u[16];
  #pragma unroll
  for (int i = 0; i < 16; ++i) u[i] = row[lane + (i << 6)];

  unsigned m = u[0];
  #pragma unroll
  for (int i = 1; i < 16; ++i) m = min(m, u[i]);
  #pragma unroll
  for (int k = 2; k <= 64; k <<= 1) {
    #pragma unroll
    for (int jj = k >> 1; jj >= 1; jj >>= 1) {
      const unsigned o = (unsigned)__shfl_xor((int)m, jj);
      const bool up    = ((lane & k) == 0);
      const bool lower = ((lane & jj) == 0);
      m = (lower == up) ? min(m, o) : max(m, o);
    }
  }
  const unsigned T = (unsigned)__shfl((int)m, 29);   // >= true rank-30 key

  unsigned mask16 = 0; int cnt = 0;
  #pragma unroll
  for (int i = 0; i < 16; ++i) {
    const bool sv = (u[i] <= T);
    mask16 |= (sv ? 1u : 0u) << i;
    cnt += sv;
  }
  int sc = cnt;
  #pragma unroll
  for (int o = 1; o < 64; o <<= 1) {
    const int v = __shfl_up(sc, o);
    if (lane >= o) sc += v;
  }
  const int base = sc - cnt;
  const int tot  = __shfl(sc, 63);
  unsigned* cb = row;                         // row data lives in regs now

  if (tot <= 64) {                            // ~always (survivors ~40±6)
    int p = base;
    #pragma unroll
    for (int i = 0; i < 16; ++i) {
      if ((mask16 >> i) & 1u) cb[p++] = u[i];
    }
    if (tot + lane < 64) cb[tot + lane] = 0xFFFFFFFFu;
    unsigned r0 = cb[lane];
    #pragma unroll
    for (int k = 2; k <= 64; k <<= 1) {
      #pragma unroll
      for (int jj = k >> 1; jj >= 1; jj >>= 1) {
        const unsigned o = (unsigned)__shfl_xor((int)r0, jj);
        const bool up    = ((lane & k) == 0);
        const bool lower = ((lane & jj) == 0);
        r0 = (lower == up) ? min(r0, o) : max(r0, o);
      }
    }
    if (lane < KNN_K) out[lane] = jbase + (int)(r0 & 1023u);
  } else if (tot <= 128) {
    int p = base;
    #pragma unroll
    for (int i = 0; i < 16; ++i) {
      if ((mask16 >> i) & 1u) cb[p++] = u[i];
    }
    for (int q = tot + lane; q < 128; q += 64) cb[q] = 0xFFFFFFFFu;
    unsigned r0 = cb[lane];
    unsigned r1 = cb[lane + 64];
    #pragma unroll
    for (int k = 2; k <= 128; k <<= 1) {
      #pragma unroll
      for (int jj = k >> 1; jj >= 1; jj >>= 1) {
        if (jj == 64) {
          const unsigned lo = min(r0, r1), hi = max(r0, r1);
          r0 = lo; r1 = hi;
        } else {
          const unsigned o0 = (unsigned)__shfl_xor((int)r0, jj);
          const unsigned o1 = (unsigned)__shfl_xor((int)r1, jj);
          const bool lower = ((lane & jj) == 0);
          const bool up0 = ((lane & k) == 0);
          const bool up1 = (((lane + 64) & k) == 0);
          r0 = (lower == up0) ? min(r0, o0) : max(r0, o0);
          r1 = (lower == up1) ? min(r1, o1) : max(r1, o1);
        }
      }
    }
    if (lane < KNN_K) out[lane] = jbase + (int)(r0 & 1023u);
  } else {                                    // exact fallback (never in practice)
    unsigned pk[16];
    #pragma unroll
    for (int i = 0; i < 16; ++i) pk[i] = u[i];
    #pragma unroll 1
    for (int k = 0; k < KNN_K; ++k) {
      unsigned best = pk[0];
      #pragma unroll
      for (int i = 1; i < 16; ++i) best = min(best, pk[i]);
      #pragma unroll
      for (int o = 32; o > 0; o >>= 1)
        best = min(best, (unsigned)__shfl_xor((int)best, o));
      if (lane == 0) out[k] = jbase + (int)(best & 1023u);
      #pragma unroll
      for (int i = 0; i < 16; ++i) if (pk[i] == best) pk[i] = 0xFFFFFFFFu;
    }
  }
}

// ---------------------------------------------------------------------------
// knn64: fused distance+select for bf16 D=64 features. One block = 16 queries.
// Phase 1: each wave computes a 16x128 chunk of D2 via 16x16x32 MFMA and
// writes PACKED keys to LDS. Phase 2: each wave selects top-30 for 2 rows.
// 66 KB LDS -> 2 blocks/CU. Grid (NPB/QB, NB), 512 threads.
// ---------------------------------------------------------------------------
__global__ __launch_bounds__(512)
void knn64_kernel(const ushort_t* __restrict__ X, int lda,
                  const float* __restrict__ sq, int* __restrict__ idx) {
  __shared__ unsigned d2l[QB * DSTR];
  __shared__ float sqa[QB];
  const int tid = threadIdx.x;
  const int wave = tid >> 6, lane = tid & 63;
  const int g = lane >> 4, r16 = lane & 15;
  const int nbase = blockIdx.y * NPB;
  const int q0 = blockIdx.x * QB;
  if (tid < QB) sqa[tid] = sq[nbase + q0 + tid];
  __syncthreads();

  const int n0 = wave * 128;
  bf16x8 a0[2];
  #pragma unroll
  for (int ks = 0; ks < 2; ++ks)
    a0[ks] = *(const bf16x8*)(X + (size_t)(nbase + q0 + r16) * lda + ks * 32 + g * 8);

  #pragma unroll
  for (int nt = 0; nt < 8; ++nt) {
    const int col = n0 + nt * 16 + r16;
    f32x4 acc0 = (f32x4)(0.f);
    #pragma unroll
    for (int ks = 0; ks < 2; ++ks) {
      const bf16x8 b = *(const bf16x8*)(X + (size_t)(nbase + col) * lda + ks * 32 + g * 8);
      acc0 = __builtin_amdgcn_mfma_f32_16x16x32_bf16(a0[ks], b, acc0, 0, 0, 0);
    }
    const float sb = sq[nbase + col];
    #pragma unroll
    for (int r = 0; r < 4; ++r) {
      const int row0 = g * 4 + r;
      d2l[row0 * DSTR + col] = packkey(sqa[row0] + sb - 2.f * acc0[r], col);
    }
  }
  __syncthreads();

  #pragma unroll 1
  for (int rr = 0; rr < 2; ++rr) {
    const int row = wave * 2 + rr;
    select_row_packed(&d2l[row * DSTR], nbase,
                      idx + (size_t)(nbase + q0 + row) * KNN_K, lane);
  }
}

// ---------------------------------------------------------------------------
// knn7: fused distance+select for fp32 D=7 (conv1, exact distances). One
// block = 16 queries; wave computes 2 cols x 16 rows (fp32 FMA, d-ascending
// order preserved), packs keys to LDS, then selects 2 rows. 512 threads.
// ---------------------------------------------------------------------------
__global__ __launch_bounds__(512)
void knn7_kernel(const float* __restrict__ pos,
                 const float* __restrict__ sq, int* __restrict__ idx) {
  __shared__ unsigned d2l[QB * DSTR];
  __shared__ float Xq[QB][8];
  __shared__ float sqa[QB];
  const int tid = threadIdx.x;
  const int wave = tid >> 6, lane = tid & 63;
  const int nbase = blockIdx.y * NPB;
  const int q0 = blockIdx.x * QB;
  if (tid < QB * 8) {
    const int row = tid >> 3, d = tid & 7;
    Xq[row][d] = (d < 7) ? pos[(size_t)(nbase + q0 + row) * 7 + d] : 0.f;
  }
  if (tid >= 256 && tid < 256 + QB) sqa[tid - 256] = sq[nbase + q0 + tid - 256];
  __syncthreads();

  const int c0 = wave * 128 + lane;           // two cols: c0, c0+64
  float xc0[7], xc1[7];
  #pragma unroll
  for (int d = 0; d < 7; ++d) {
    xc0[d] = pos[(size_t)(nbase + c0) * 7 + d];
    xc1[d] = pos[(size_t)(nbase + c0 + 64) * 7 + d];
  }
  const float sb0 = sq[nbase + c0], sb1 = sq[nbase + c0 + 64];
  #pragma unroll 1
  for (int row = 0; row < QB; ++row) {
    float q[7];
    #pragma unroll
    for (int d = 0; d < 7; ++d) q[d] = Xq[row][d];
    float d0 = 0.f, d1 = 0.f;
    #pragma unroll
    for (int d = 0; d < 7; ++d) { d0 += q[d] * xc0[d]; d1 += q[d] * xc1[d]; }
    const float sa = sqa[row];
    d2l[row * DSTR + c0]      = packkey(sa + sb0 - 2.f * d0, c0);
    d2l[row * DSTR + c0 + 64] = packkey(sa + sb1 - 2.f * d1, c0 + 64);
  }
  __syncthreads();

  #pragma unroll 1
  for (int rr = 0; rr < 2; ++rr) {
    const int row = wave * 2 + rr;
    select_row_packed(&d2l[row * DSTR], nbase,
                      idx + (size_t)(nbase + q0 + row) * KNN_K, lane);
  }
}

// ---------------------------------------------------------------------------
// sq (f32 / bf16 input): ||x||^2 per node (kNN path).
// ---------------------------------------------------------------------------
template<int D>
__global__ __launch_bounds__(256)
void sq_kernel(const float* __restrict__ x, int lda, float* __restrict__ sq) {
  const int wave = threadIdx.x >> 6, c = threadIdx.x & 63;
  const int nb = blockIdx.x * 16 + wave * 4;
  #pragma unroll
  for (int i = 0; i < 4; ++i) {
    const float xv = (c < D) ? x[(size_t)(nb + i) * lda + c] : 0.f;
    float p = xv * xv;
    #pragma unroll
    for (int o = 32; o > 0; o >>= 1) p += __shfl_down(p, o);
    if (c == 0) sq[nb + i] = p;
  }
}
__global__ __launch_bounds__(256)
void sqbf_kernel(const ushort_t* __restrict__ x, int lda, float* __restrict__ sq) {
  const int wave = threadIdx.x >> 6, c = threadIdx.x & 63;
  const int nb = blockIdx.x * 16 + wave * 4;
  #pragma unroll
  for (int i = 0; i < 4; ++i) {
    const float xv = bf2f(x[(size_t)(nb + i) * lda + c]);
    float p = xv * xv;
    #pragma unroll
    for (int o = 32; o > 0; o >>= 1) p += __shfl_down(p, o);
    if (c == 0) sq[nb + i] = p;
  }
}

// ---------------------------------------------------------------------------
// wprep / pospad / wcvt: weight & input prep (BN folded, bf16, transposed).
// ---------------------------------------------------------------------------
__global__ __launch_bounds__(256)
void wprep_kernel(const float* __restrict__ W1, const float* __restrict__ b1,
                  const float* __restrict__ s, const float* __restrict__ t,
                  int D, ushort_t* __restrict__ BTc, float* __restrict__ biasc) {
  const int i = blockIdx.x * 256 + threadIdx.x;
  if (i >= 128 * 64) return;
  const int n = i >> 6, k = i & 63;
  float v = 0.f;
  if (k < D) {
    if (n < 64) v = (W1[k * 64 + n] - W1[(D + k) * 64 + n]) * s[n];
    else        v = W1[(D + k) * 64 + (n - 64)] * s[n - 64];
  }
  BTc[i] = f2bf(v);
  if (k == 0) biasc[n] = (n < 64) ? (b1[n] * s[n] + t[n]) : 0.f;
}

__global__ __launch_bounds__(256)
void pospad_kernel(const float* __restrict__ pos, ushort_t* __restrict__ xpad) {
  const int i = blockIdx.x * 256 + threadIdx.x;
  const int node = i >> 6, k = i & 63;
  xpad[i] = f2bf(k < 7 ? pos[(size_t)node * 7 + k] : 0.f);
}

__global__ __launch_bounds__(256)
void wcvt_kernel(const float* __restrict__ W, ushort_t* __restrict__ BT,
                 int K, int N) {
  const int i = blockIdx.x * 256 + threadIdx.x;
  if (i >= N * K) return;
  const int n = i / K, k = i % K;
  BT[i] = f2bf(W[(size_t)k * N + n]);
}

// ---------------------------------------------------------------------------
// edge (MFMA): per node, H[32 edges][64] @ W2[64][64] -> col-max over edges.
// W2T pre-transposed bf16 [n][k]; 4 nodes per wave. av[node][128]: as|vs.
// ---------------------------------------------------------------------------
__global__ __launch_bounds__(256)
void edge_mfma_kernel(const ushort_t* __restrict__ av,
                      const int* __restrict__ idx,
                      const ushort_t* __restrict__ W2T, const float* __restrict__ b2,
                      ushort_t* __restrict__ xbf) {
  const int lane = threadIdx.x & 63;
  const int wave = threadIdx.x >> 6;
  const int g = lane >> 4, r16 = lane & 15;
  const int node0 = blockIdx.x * 16 + wave * 4;

  bf16x8 bf[2][4];
  #pragma unroll
  for (int ks = 0; ks < 2; ++ks)
    #pragma unroll
    for (int nt = 0; nt < 4; ++nt)
      bf[ks][nt] = *(const bf16x8*)(W2T + (nt * 16 + r16) * 64 + ks * 32 + g * 8);

  const float b2c = b2[lane];

  #pragma unroll 1
  for (int nn = 0; nn < 4; ++nn) {
    const int node = node0 + nn;
    float asf[2][8];
    {
      const ushort_t* ar = av + (size_t)node * 128;
      #pragma unroll
      for (int ks = 0; ks < 2; ++ks) {
        union { uint4 v; ushort_t s[8]; } u;
        u.v = *(const uint4*)(ar + ks * 32 + g * 8);
        #pragma unroll
        for (int i = 0; i < 8; ++i) asf[ks][i] = bf2f(u.s[i]);
      }
    }
    const int j0 = idx[(size_t)node * KNN_K + r16];
    const int e1 = 16 + r16;
    const int j1 = idx[(size_t)node * KNN_K + (e1 < KNN_K ? e1 : KNN_K - 1)];

    f32x4 acc[2][4];
    #pragma unroll
    for (int mt = 0; mt < 2; ++mt)
      #pragma unroll
      for (int nt = 0; nt < 4; ++nt) acc[mt][nt] = (f32x4)(0.f);

    #pragma unroll
    for (int mt = 0; mt < 2; ++mt) {
      const int j = mt ? j1 : j0;
      const ushort_t* vr = av + (size_t)j * 128 + 64;
      #pragma unroll
      for (int ks = 0; ks < 2; ++ks) {
        union { uint4 v; ushort_t s[8]; } u;
        u.v = *(const uint4*)(vr + ks * 32 + g * 8);
        bf16x8 af;
        #pragma unroll
        for (int i = 0; i < 8; ++i) {
          const float hh = fmaxf(asf[ks][i] + bf2f(u.s[i]), 0.f);
          af[i] = (short)f2bf(hh);
        }
        #pragma unroll
        for (int nt = 0; nt < 4; ++nt)
          acc[mt][nt] = __builtin_amdgcn_mfma_f32_16x16x32_bf16(af, bf[ks][nt], acc[mt][nt], 0, 0, 0);
      }
    }

    float cm[4];
    #pragma unroll
    for (int nt = 0; nt < 4; ++nt) {
      float m0 = fmaxf(fmaxf(acc[0][nt][0], acc[0][nt][1]), fmaxf(acc[0][nt][2], acc[0][nt][3]));
      float m1 = fmaxf(fmaxf(acc[1][nt][0], acc[1][nt][1]), fmaxf(acc[1][nt][2], acc[1][nt][3]));
      float m = fmaxf(m0, m1);
      m = fmaxf(m, __shfl_xor(m, 16));
      m = fmaxf(m, __shfl_xor(m, 32));
      cm[nt] = m;
    }
    const float v = (g == 0) ? cm[0] : (g == 1) ? cm[1] : (g == 2) ? cm[2] : cm[3];
    xbf[(size_t)node * 192 + lane] = f2bf(v + b2c);
  }
}

// ---------------------------------------------------------------------------
// bf16 MFMA GEMM: C = relu?(A[M,K]bf16 @ B + bias). B passed as BT[N][K] bf16.
// BM=128 BN=128 BK=64, 4 waves (2x2), wave tile 64x64.
// ---------------------------------------------------------------------------
template<bool RELU, typename CT>
__global__ __launch_bounds__(256)
void gemm_bf16_kernel(const ushort_t* __restrict__ A, int lda,
                      const ushort_t* __restrict__ BT, int ldb,
                      const float* __restrict__ bias,
                      CT* __restrict__ C, int ldc, int K) {
  __shared__ ushort_t As[128 * 72];
  __shared__ ushort_t Bs[128 * 72];
  const int tid = threadIdx.x;
  const int lane = tid & 63;
  const int g = lane >> 4, r16 = lane & 15;
  const int wv = tid >> 6, wm = wv >> 1, wn = wv & 1;
  const int bm = blockIdx.x * 128, bn = blockIdx.y * 128;

  f32x4 acc[4][4];
  #pragma unroll
  for (int mt = 0; mt < 4; ++mt)
    #pragma unroll
    for (int nt = 0; nt < 4; ++nt) acc[mt][nt] = (f32x4)(0.f);

  const int srow = tid >> 1, scq = (tid & 1) * 32;
  for (int k0 = 0; k0 < K; k0 += 64) {
    const ushort_t* ap = A + (size_t)(bm + srow) * lda + k0 + scq;
    const ushort_t* bp = BT + (size_t)(bn + srow) * ldb + k0 + scq;
    uint4 av0 = *(const uint4*)(ap);      uint4 av1 = *(const uint4*)(ap + 8);
    uint4 av2 = *(const uint4*)(ap + 16); uint4 av3 = *(const uint4*)(ap + 24);
    uint4 bv0 = *(const uint4*)(bp);      uint4 bv1 = *(const uint4*)(bp + 8);
    uint4 bv2 = *(const uint4*)(bp + 16); uint4 bv3 = *(const uint4*)(bp + 24);
    __syncthreads();
    *(uint4*)(As + srow * 72 + scq +  0) = av0;
    *(uint4*)(As + srow * 72 + scq +  8) = av1;
    *(uint4*)(As + srow * 72 + scq + 16) = av2;
    *(uint4*)(As + srow * 72 + scq + 24) = av3;
    *(uint4*)(Bs + srow * 72 + scq +  0) = bv0;
    *(uint4*)(Bs + srow * 72 + scq +  8) = bv1;
    *(uint4*)(Bs + srow * 72 + scq + 16) = bv2;
    *(uint4*)(Bs + srow * 72 + scq + 24) = bv3;
    __syncthreads();
    #pragma unroll
    for (int ks = 0; ks < 2; ++ks) {
      bf16x8 a[4], b[4];
      #pragma unroll
      for (int mt = 0; mt < 4; ++mt)
        a[mt] = *(const bf16x8*)(As + (wm * 64 + mt * 16 + r16) * 72 + ks * 32 + g * 8);
      #pragma unroll
      for (int nt = 0; nt < 4; ++nt)
        b[nt] = *(const bf16x8*)(Bs + (wn * 64 + nt * 16 + r16) * 72 + ks * 32 + g * 8);
      #pragma unroll
      for (int mt = 0; mt < 4; ++mt)
        #pragma unroll
        for (int nt = 0; nt < 4; ++nt)
          acc[mt][nt] = __builtin_amdgcn_mfma_f32_16x16x32_bf16(a[mt], b[nt], acc[mt][nt], 0, 0, 0);
    }
  }

  #pragma unroll
  for (int nt = 0; nt < 4; ++nt) {
    const int col = bn + wn * 64 + nt * 16 + r16;
    const float bv = bias[col];
    #pragma unroll
    for (int mt = 0; mt < 4; ++mt) {
      #pragma unroll
      for (int r = 0; r < 4; ++r) {
        const int row = bm + wm * 64 + mt * 16 + g * 4 + r;
        float val = acc[mt][nt][r] + bv;
        if (RELU) val = fmaxf(val, 0.f);
        if constexpr (sizeof(CT) == 2) C[(size_t)row * ldc + col] = f2bf(val);
        else                           C[(size_t)row * ldc + col] = val;
      }
    }
  }
}

// ---------------------------------------------------------------------------
// g4: logits = h3[row](bf16) @ W4[128,2] + b4 ; log_softmax. 4 rows/block.
// ---------------------------------------------------------------------------
__global__ __launch_bounds__(256)
void g4_kernel(const ushort_t* __restrict__ h3, const float* __restrict__ W4,
               const float* __restrict__ b4, float* __restrict__ seg) {
  const int row = blockIdx.x * 4 + (threadIdx.x >> 6);
  const int lane = threadIdx.x & 63;
  const ushort_t* hr = h3 + (size_t)row * 128;
  float p0 = 0.f, p1 = 0.f;
  #pragma unroll
  for (int h = 0; h < 2; ++h) {
    const int r = lane + h * 64;
    const float hv = bf2f(hr[r]);
    p0 += hv * W4[r * 2 + 0];
    p1 += hv * W4[r * 2 + 1];
  }
  #pragma unroll
  for (int o = 32; o > 0; o >>= 1) { p0 += __shfl_down(p0, o); p1 += __shfl_down(p1, o); }
  if (lane == 0) {
    const float l0 = p0 + b4[0], l1 = p1 + b4[1];
    const float mx = fmaxf(l0, l1);
    const float lse = mx + logf(expf(l0 - mx) + expf(l1 - mx));
    seg[(size_t)row * 2 + 0] = l0 - lse;
    seg[(size_t)row * 2 + 1] = l1 - lse;
  }
}

// ---------------------------------------------------------------------------
// wrapper: per event: y = relu(flat @ mW1 + mb1) @ mW2 + mb2 ; log_softmax.
// ---------------------------------------------------------------------------
__global__ __launch_bounds__(256)
void wrapper_kernel(const float* __restrict__ seg, const float* __restrict__ W1,
                    const float* __restrict__ b1, const float* __restrict__ W2,
                    const float* __restrict__ b2, float* __restrict__ out) {
  __shared__ float fl[NPB * 2];
  __shared__ float part[2][128];
  __shared__ float y1[100];
  __shared__ float l2[2];
  const int b = blockIdx.x, tid = threadIdx.x;
  for (int i = tid; i < NPB * 2; i += 256) fl[i] = seg[(size_t)b * NPB * 2 + i];
  __syncthreads();
  {
    const int c = tid & 127, p = tid >> 7;
    float acc = 0.f;
    if (c < 100) {
      const int r0 = p * (NPB);
      #pragma unroll 16
      for (int r = 0; r < NPB; ++r)
        acc += fl[r0 + r] * W1[(size_t)(r0 + r) * 100 + c];
    }
    part[p][c] = acc;
  }
  __syncthreads();
  if (tid < 100) {
    y1[tid] = fmaxf(part[0][tid] + part[1][tid] + b1[tid], 0.f);
  }
  __syncthreads();
  if (tid < 2) {
    float acc = b2[tid];
    for (int j = 0; j < 100; ++j) acc += y1[j] * W2[j * 2 + tid];
    l2[tid] = acc;
  }
  __syncthreads();
  if (tid == 0) {
    const float l0 = l2[0], l1 = l2[1];
    const float mx = fmaxf(l0, l1);
    const float lse = mx + logf(expf(l0 - mx) + expf(l1 - mx));
    out[b * 2 + 0] = l0 - lse;
    out[b * 2 + 1] = l1 - lse;
  }
}

// ---------------------------------------------------------------------------
extern "C" void kernel_launch(void* const* d_in, const int* in_sizes, int n_in,
                              void* d_out, int out_size, void* d_ws, size_t ws_size,
                              hipStream_t stream) {
  const float* pos   = (const float*)d_in[0];
  const float* c1_W1 = (const float*)d_in[3];
  const float* c1_b1 = (const float*)d_in[4];
  const float* c1_s  = (const float*)d_in[5];
  const float* c1_t  = (const float*)d_in[6];
  const float* c1_W2 = (const float*)d_in[7];
  const float* c1_b2 = (const float*)d_in[8];
  const float* c2_W1 = (const float*)d_in[9];
  const float* c2_b1 = (const float*)d_in[10];
  const float* c2_s  = (const float*)d_in[11];
  const float* c2_t  = (const float*)d_in[12];
  const float* c2_W2 = (const float*)d_in[13];
  const float* c2_b2 = (const float*)d_in[14];
  const float* c3_W1 = (const float*)d_in[15];
  const float* c3_b1 = (const float*)d_in[16];
  const float* c3_s  = (const float*)d_in[17];
  const float* c3_t  = (const float*)d_in[18];
  const float* c3_W2 = (const float*)d_in[19];
  const float* c3_b2 = (const float*)d_in[20];
  const float* h_W1  = (const float*)d_in[21];
  const float* h_b1  = (const float*)d_in[22];
  const float* h_W2  = (const float*)d_in[23];
  const float* h_b2  = (const float*)d_in[24];
  const float* h_W3  = (const float*)d_in[25];
  const float* h_b3  = (const float*)d_in[26];
  const float* h_W4  = (const float*)d_in[27];
  const float* h_b4  = (const float*)d_in[28];
  const float* m_W1  = (const float*)d_in[29];
  const float* m_b1  = (const float*)d_in[30];
  const float* m_W2  = (const float*)d_in[31];
  const float* m_b2  = (const float*)d_in[32];

  float* ws = (float*)d_ws;
  size_t off = 0;
  auto alloc = [&](size_t n) {
    float* p = ws + off;
    off += (n + 63) & ~(size_t)63;
    return p;
  };
  ushort_t* xbf   = (ushort_t*)alloc((size_t)NTOT * 96);  // bf16 features [NTOT][192]
  int*      idx   = (int*)alloc((size_t)NTOT * KNN_K);
  ushort_t* avbuf = (ushort_t*)alloc((size_t)NTOT * 64);  // as|vs bf16 [NTOT][128]
  ushort_t* xpad  = (ushort_t*)alloc((size_t)NTOT * 32);  // pos bf16 [NTOT][64]
  float*    sqb   = alloc(NTOT);
  float*    seg   = alloc((size_t)NTOT * 2);
  ushort_t* BT1   = (ushort_t*)alloc(1024 * 192 / 2);
  ushort_t* BT2   = (ushort_t*)alloc(256 * 1024 / 2);
  ushort_t* BT3   = (ushort_t*)alloc(128 * 256 / 2);
  ushort_t* BTc1  = (ushort_t*)alloc(128 * 64 / 2);
  ushort_t* BTc2  = (ushort_t*)alloc(128 * 64 / 2);
  ushort_t* BTc3  = (ushort_t*)alloc(128 * 64 / 2);
  ushort_t* W2T1  = (ushort_t*)alloc(64 * 64 / 2);
  ushort_t* W2T2  = (ushort_t*)alloc(64 * 64 / 2);
  ushort_t* W2T3  = (ushort_t*)alloc(64 * 64 / 2);
  float*    bc1   = alloc(128);
  float*    bc2   = alloc(128);
  float*    bc3   = alloc(128);

  // Head activations.
  const size_t totf = ws_size / 4;
  const size_t avail = (totf > off + 1024) ? (totf - off - 1024) : 0;
  int CH = 1;
  while (CH < 256 && (size_t)(NTOT / CH) * 704 > avail) CH <<= 1;
  const int CR = NTOT / CH;
  ushort_t* h1 = (ushort_t*)(ws + off);
  ushort_t* h2 = h1 + (size_t)CR * 1024;
  ushort_t* h3 = h2 + (size_t)CR * 256;

  // ---- one-time prep (deterministic every launch)
  wcvt_kernel<<<(192 * 1024 + 255) / 256, 256, 0, stream>>>(h_W1, BT1, 192, 1024);
  wcvt_kernel<<<(1024 * 256 + 255) / 256, 256, 0, stream>>>(h_W2, BT2, 1024, 256);
  wcvt_kernel<<<(256 * 128 + 255) / 256, 256, 0, stream>>>(h_W3, BT3, 256, 128);
  wcvt_kernel<<<16, 256, 0, stream>>>(c1_W2, W2T1, 64, 64);
  wcvt_kernel<<<16, 256, 0, stream>>>(c2_W2, W2T2, 64, 64);
  wcvt_kernel<<<16, 256, 0, stream>>>(c3_W2, W2T3, 64, 64);
  wprep_kernel<<<32, 256, 0, stream>>>(c1_W1, c1_b1, c1_s, c1_t, 7,  BTc1, bc1);
  wprep_kernel<<<32, 256, 0, stream>>>(c2_W1, c2_b1, c2_s, c2_t, 64, BTc2, bc2);
  wprep_kernel<<<32, 256, 0, stream>>>(c3_W1, c3_b1, c3_s, c3_t, 64, BTc3, bc3);
  pospad_kernel<<<NTOT * 64 / 256, 256, 0, stream>>>(pos, xpad);

  // as/vs GEMM: avbuf[NTOT][128] = A[NTOT][64] @ BTc^T + bias
  auto run_av = [&](const ushort_t* A, int lda, const ushort_t* BTc, const float* bc) {
    gemm_bf16_kernel<false, ushort_t><<<dim3(NTOT / 128, 1), 256, 0, stream>>>(
        A, lda, BTc, 64, bc, avbuf, 128, 64);
  };

  // ---- conv1 (pos f32 exact kNN, D=7) -> xbf cols 0..63
  sq_kernel<7><<<NTOT / 16, 256, 0, stream>>>(pos, 7, sqb);
  run_av(xpad, 64, BTc1, bc1);
  knn7_kernel<<<dim3(NPB / QB, NB), 512, 0, stream>>>(pos, sqb, idx);
  edge_mfma_kernel<<<NTOT / 16, 256, 0, stream>>>(avbuf, idx, W2T1, c1_b2, xbf + 0);

  // ---- conv2 (x1 bf16, D=64) -> cols 64..127
  sqbf_kernel<<<NTOT / 16, 256, 0, stream>>>(xbf + 0, 192, sqb);
  run_av(xbf + 0, 192, BTc2, bc2);
  knn64_kernel<<<dim3(NPB / QB, NB), 512, 0, stream>>>(xbf + 0, 192, sqb, idx);
  edge_mfma_kernel<<<NTOT / 16, 256, 0, stream>>>(avbuf, idx, W2T2, c2_b2, xbf + 64);

  // ---- conv3 (x2 bf16, D=64) -> cols 128..191
  sqbf_kernel<<<NTOT / 16, 256, 0, stream>>>(xbf + 64, 192, sqb);
  run_av(xbf + 64, 192, BTc3, bc3);
  knn64_kernel<<<dim3(NPB / QB, NB), 512, 0, stream>>>(xbf + 64, 192, sqb, idx);
  edge_mfma_kernel<<<NTOT / 16, 256, 0, stream>>>(avbuf, idx, W2T3, c3_b2, xbf + 128);

  // ---- head MLP (bf16 MFMA, chunked) + per-node log_softmax
  for (int ch = 0; ch < CH; ++ch) {
    const ushort_t* Ax = xbf + (size_t)ch * CR * 192;
    gemm_bf16_kernel<true, ushort_t><<<dim3(CR / 128, 8), 256, 0, stream>>>(Ax, 192, BT1, 192, h_b1, h1, 1024, 192);
    gemm_bf16_kernel<true, ushort_t><<<dim3(CR / 128, 2), 256, 0, stream>>>(h1, 1024, BT2, 1024, h_b2, h2, 256, 1024);
    gemm_bf16_kernel<true, ushort_t><<<dim3(CR / 128, 1), 256, 0, stream>>>(h2, 256, BT3, 256, h_b3, h3, 128, 256);
    g4_kernel<<<CR / 4, 256, 0, stream>>>(h3, h_W4, h_b4, seg + (size_t)ch * CR * 2);
  }

  // ---- wrapper MLP per event
  wrapper_kernel<<<NB, 256, 0, stream>>>(seg, m_W1, m_b1, m_W2, m_b2, (float*)d_out);
}